// Round 1
// baseline (49.869 us; speedup 1.0000x reference)
//
#include <hip/hip_runtime.h>

// HGate on qubits (0,1,2) of a 13-qubit state, D=2, N=8192, B=4096.
// Rows n = (j<<10)|g for j in [0,8) are combined by an 8-point
// Walsh-Hadamard transform scaled by 2^{-3/2}. Batch dim (4096 f32 per row)
// is contiguous -> float4 vectorized, fully coalesced.

__device__ __forceinline__ float4 f4add(const float4& a, const float4& b) {
    return make_float4(a.x + b.x, a.y + b.y, a.z + b.z, a.w + b.w);
}
__device__ __forceinline__ float4 f4sub(const float4& a, const float4& b) {
    return make_float4(a.x - b.x, a.y - b.y, a.z - b.z, a.w - b.w);
}
__device__ __forceinline__ float4 f4scl(const float4& a, float s) {
    return make_float4(a.x * s, a.y * s, a.z * s, a.w * s);
}

__global__ __launch_bounds__(256) void hgate8_kernel(const float* __restrict__ x,
                                                     float* __restrict__ y) {
    // 1,048,576 threads total: 1024 low-bit groups x 1024 float4 column chunks.
    const unsigned t   = blockIdx.x * 256u + threadIdx.x;
    const unsigned col = t & 1023u;   // float4 column index, B/4 = 1024
    const unsigned g   = t >> 10;     // low-10-bit row group, 0..1023

    // float4-unit addressing: row stride = B/4 = 1024; j-stride = 1024*1024.
    const size_t base = (size_t)g * 1024u + col;
    const size_t jstr = 1048576u;     // 1024 rows * 1024 float4/row

    const float4* __restrict__ xv = (const float4*)x;
    float4* __restrict__ yv = (float4*)y;

    float4 v0 = xv[base + 0 * jstr];
    float4 v1 = xv[base + 1 * jstr];
    float4 v2 = xv[base + 2 * jstr];
    float4 v3 = xv[base + 3 * jstr];
    float4 v4 = xv[base + 4 * jstr];
    float4 v5 = xv[base + 5 * jstr];
    float4 v6 = xv[base + 6 * jstr];
    float4 v7 = xv[base + 7 * jstr];

    // 8-point FWHT (bit order irrelevant: H on each bit commutes).
    // stage 1: pairs differing in bit0
    float4 a0 = f4add(v0, v1), a1 = f4sub(v0, v1);
    float4 a2 = f4add(v2, v3), a3 = f4sub(v2, v3);
    float4 a4 = f4add(v4, v5), a5 = f4sub(v4, v5);
    float4 a6 = f4add(v6, v7), a7 = f4sub(v6, v7);
    // stage 2: bit1
    float4 b0 = f4add(a0, a2), b2 = f4sub(a0, a2);
    float4 b1 = f4add(a1, a3), b3 = f4sub(a1, a3);
    float4 b4 = f4add(a4, a6), b6 = f4sub(a4, a6);
    float4 b5 = f4add(a5, a7), b7 = f4sub(a5, a7);
    // stage 3: bit2
    float4 c0 = f4add(b0, b4), c4 = f4sub(b0, b4);
    float4 c1 = f4add(b1, b5), c5 = f4sub(b1, b5);
    float4 c2 = f4add(b2, b6), c6 = f4sub(b2, b6);
    float4 c3 = f4add(b3, b7), c7 = f4sub(b3, b7);

    const float s = 0.35355339059327379f;  // 2^{-3/2}

    yv[base + 0 * jstr] = f4scl(c0, s);
    yv[base + 1 * jstr] = f4scl(c1, s);
    yv[base + 2 * jstr] = f4scl(c2, s);
    yv[base + 3 * jstr] = f4scl(c3, s);
    yv[base + 4 * jstr] = f4scl(c4, s);
    yv[base + 5 * jstr] = f4scl(c5, s);
    yv[base + 6 * jstr] = f4scl(c6, s);
    yv[base + 7 * jstr] = f4scl(c7, s);
}

extern "C" void kernel_launch(void* const* d_in, const int* in_sizes, int n_in,
                              void* d_out, int out_size, void* d_ws, size_t ws_size,
                              hipStream_t stream) {
    const float* x = (const float*)d_in[0];
    // d_in[1] is the 2x2 Hadamard matrix; for D=2 it is exactly
    // [[1,1],[1,-1]]/sqrt(2) (real), hard-coded in the butterfly above.
    float* y = (float*)d_out;

    // 1024 groups * 1024 float4 columns = 1,048,576 threads = 4096 blocks x 256.
    hgate8_kernel<<<4096, 256, 0, stream>>>(x, y);
}